// Round 1
// baseline (431.011 us; speedup 1.0000x reference)
//
#include <hip/hip_runtime.h>

// Problem constants (from reference):
//   obj   : [1, 2048, 2048] fp32      (in_sizes[0] = 4,194,304)
//   waves : [4, 1024, 128, 128] fp32  (in_sizes[1] = 67,108,864)
//   pos   : [1024, 2] int32           (in_sizes[2] = 2,048), values in [0,1920)
// Outputs (concatenated in d_out, fp32):
//   patches     : [1024, 1, 128, 128] = 16,777,216 elems
//   object_norm : [2048, 2048]        =  4,194,304 elems
//
// R1: factor the 4-mode reduction out of the tile gather.
//   Kernel A (streaming): crop + patch_norm = sum_m waves^2 -> ws + binning.
//   Kernel B (gather):    norm from patch_norm, 1 load/pixel/batch (was 8),
//                         and patch_norm is L3-resident when B runs.
// Gathered read volume: ~603 MB -> ~151 MB; waves read once, coalesced.

#define NMODES 4
#define NB     1024
#define PH     128
#define PW     128
#define OH     2048
#define OW     2048

#define TS       64              // object tile size (64x64)
#define NT_X     (OW / TS)       // 32
#define NT_Y     (OH / TS)       // 32
#define NT       (NT_X * NT_Y)   // 1024 tiles
#define CAP      128             // max batches listed per tile (avg ~10)
#define SLICES   8               // row-slices per tile -> 8192 blocks
#define UNROLL   4

// ---------------------------------------------------------------------------
// Kernel A: crop + 4-mode reduce + binning. One thread per aligned w-quad.
// ---------------------------------------------------------------------------
__global__ __launch_bounds__(256) void crop_reduce_bin(
    const float* __restrict__ obj,
    const float* __restrict__ waves,
    const int*   __restrict__ pos,
    float* __restrict__ patches,
    float* __restrict__ pnorm,        // [NB, PH, PW] in workspace
    int*   __restrict__ tile_cnt,
    int*   __restrict__ tile_list)
{
    const int q = blockIdx.x * blockDim.x + threadIdx.x;

    if (q < NB) {
        const int r0 = pos[2 * q];
        const int c0 = pos[2 * q + 1];
        const int ty0 = r0 >> 6, ty1 = (r0 + PH - 1) >> 6;
        const int tx0 = c0 >> 6, tx1 = (c0 + PW - 1) >> 6;
        for (int ty = ty0; ty <= ty1; ++ty)
            for (int tx = tx0; tx <= tx1; ++tx) {
                const int t = ty * NT_X + tx;
                const int idx = atomicAdd(&tile_cnt[t], 1);
                if (idx < CAP) tile_list[t * CAP + idx] = q;
            }
    }

    const int b     = q >> 12;          // quads per batch = PH*PW/4 = 4096
    const int local = q & 4095;
    const int h     = local >> 5;       // 32 quads per row
    const int w     = (local & 31) << 2;

    const int r0 = pos[b * 2 + 0];
    const int c0 = pos[b * 2 + 1];

    // crop: patches[b,h,w..w+3] = obj[r0+h, c0+w..w+3] (unaligned source)
    const int oidx = (r0 + h) * OW + (c0 + w);
    float4 p;
    p.x = obj[oidx + 0];
    p.y = obj[oidx + 1];
    p.z = obj[oidx + 2];
    p.w = obj[oidx + 3];
    const int pbase = b * (PH * PW) + h * PW + w;   // 16B-aligned
    *reinterpret_cast<float4*>(patches + pbase) = p;

    // mode reduce: pnorm[b,h,w..w+3] = sum_m waves[m,b,h,w..w+3]^2
    const int MS = NB * PH * PW;        // mode stride (64 MiB / 4B)
    const float4 w0 = *reinterpret_cast<const float4*>(waves + pbase);
    const float4 w1 = *reinterpret_cast<const float4*>(waves + MS + pbase);
    const float4 w2 = *reinterpret_cast<const float4*>(waves + 2 * MS + pbase);
    const float4 w3 = *reinterpret_cast<const float4*>(waves + 3 * MS + pbase);
    float4 s;
    s.x = w0.x * w0.x + w1.x * w1.x + w2.x * w2.x + w3.x * w3.x;
    s.y = w0.y * w0.y + w1.y * w1.y + w2.y * w2.y + w3.y * w3.y;
    s.z = w0.z * w0.z + w1.z * w1.z + w2.z * w2.z + w3.z * w3.z;
    s.w = w0.w * w0.w + w1.w * w1.w + w2.w * w2.w + w3.w * w3.w;
    *reinterpret_cast<float4*>(pnorm + pbase) = s;
}

// ---------------------------------------------------------------------------
// Kernel B: object_norm gather from patch_norm. 1024 tiles x 8 row-slices;
// 256 threads/block, 2 pixels/thread. Branchless clamped loads.
// ---------------------------------------------------------------------------
__global__ __launch_bounds__(256) void norm_gather_pn(
    const float* __restrict__ pnorm,
    const int*   __restrict__ pos,
    const int*   __restrict__ tile_cnt,
    const int*   __restrict__ tile_list,
    float* __restrict__ norm)
{
    const int blk = blockIdx.x;
    const int t   = blk >> 3;           // tile id
    const int s   = blk & 7;            // row-slice within tile
    const int Y0  = (t >> 5) * TS + s * (TS / SLICES);
    const int X0  = (t & 31) * TS;

    __shared__ int s_base[CAP + UNROLL];
    __shared__ int s_r[CAP + UNROLL];
    __shared__ int s_c[CAP + UNROLL];

    const int count = min(tile_cnt[t], CAP);
    const int cpad  = (count + UNROLL - 1) & ~(UNROLL - 1);
    for (int i = threadIdx.x; i < cpad; i += 256) {
        if (i < count) {
            const int b = tile_list[t * CAP + i];
            s_base[i] = b * (PH * PW);
            s_r[i]    = pos[2 * b];
            s_c[i]    = pos[2 * b + 1];
        } else {
            s_base[i] = 0;              // dummy: mask always 0; clamped loads
            s_r[i]    = 1 << 20;        // read pnorm[0..] (safe)
            s_c[i]    = 1 << 20;
        }
    }
    __syncthreads();

    const int x     = threadIdx.x & 63; // 64 lanes span one tile row
    const int phase = threadIdx.x >> 6; // 0..3
    const int X     = X0 + x;
    const int Ya    = Y0 + phase;       // first owned row
    const int Yb    = Ya + 4;           // second owned row

    float acc_a = 0.0f;
    float acc_b = 0.0f;

    #pragma unroll 4
    for (int i = 0; i < cpad; ++i) {
        const int dra = Ya - s_r[i];    // broadcast LDS reads (conflict-free)
        const int drb = Yb - s_r[i];
        const int dc  = X  - s_c[i];

        const bool va = ((unsigned)dc < (unsigned)PW) &
                        ((unsigned)dra < (unsigned)PH);
        const bool vb = ((unsigned)dc < (unsigned)PW) &
                        ((unsigned)drb < (unsigned)PH);

        const int dcc  = min(max(dc, 0),  PW - 1);
        const int drac = min(max(dra, 0), PH - 1);
        const int drbc = min(max(drb, 0), PH - 1);

        const float sa = pnorm[s_base[i] + drac * PW + dcc];
        const float sb = pnorm[s_base[i] + drbc * PW + dcc];

        acc_a += va ? sa : 0.0f;        // v_cndmask + v_add (no branch)
        acc_b += vb ? sb : 0.0f;
    }

    norm[Ya * OW + X] = acc_a;          // every pixel written exactly once
    norm[Yb * OW + X] = acc_b;
}

// ---------------------------------------------------------------------------
// Fallback path (only if ws is too small for patch_norm): old behavior.
// ---------------------------------------------------------------------------
__global__ __launch_bounds__(256) void crop_and_bin(
    const float* __restrict__ obj,
    const int*   __restrict__ pos,
    float* __restrict__ patches,
    int*   __restrict__ tile_cnt,
    int*   __restrict__ tile_list)
{
    const int q = blockIdx.x * blockDim.x + threadIdx.x;

    if (q < NB) {
        const int r0 = pos[2 * q];
        const int c0 = pos[2 * q + 1];
        const int ty0 = r0 >> 6, ty1 = (r0 + PH - 1) >> 6;
        const int tx0 = c0 >> 6, tx1 = (c0 + PW - 1) >> 6;
        for (int ty = ty0; ty <= ty1; ++ty)
            for (int tx = tx0; tx <= tx1; ++tx) {
                const int t = ty * NT_X + tx;
                const int idx = atomicAdd(&tile_cnt[t], 1);
                if (idx < CAP) tile_list[t * CAP + idx] = q;
            }
    }

    const int b     = q >> 12;
    const int local = q & 4095;
    const int h     = local >> 5;
    const int w     = (local & 31) << 2;

    const int r0 = pos[b * 2 + 0];
    const int c0 = pos[b * 2 + 1];

    const int oidx = (r0 + h) * OW + (c0 + w);
    float4 p;
    p.x = obj[oidx + 0];
    p.y = obj[oidx + 1];
    p.z = obj[oidx + 2];
    p.w = obj[oidx + 3];
    *reinterpret_cast<float4*>(patches + b * (PH * PW) + h * PW + w) = p;
}

__global__ __launch_bounds__(256) void norm_gather_waves(
    const float* __restrict__ waves,
    const int*   __restrict__ pos,
    const int*   __restrict__ tile_cnt,
    const int*   __restrict__ tile_list,
    float* __restrict__ norm)
{
    const int blk = blockIdx.x;
    const int t   = blk >> 3;
    const int s   = blk & 7;
    const int Y0  = (t >> 5) * TS + s * (TS / SLICES);
    const int X0  = (t & 31) * TS;

    __shared__ int s_base[CAP + UNROLL];
    __shared__ int s_r[CAP + UNROLL];
    __shared__ int s_c[CAP + UNROLL];

    const int count = min(tile_cnt[t], CAP);
    const int cpad  = (count + UNROLL - 1) & ~(UNROLL - 1);
    for (int i = threadIdx.x; i < cpad; i += 256) {
        if (i < count) {
            const int b = tile_list[t * CAP + i];
            s_base[i] = b * (PH * PW);
            s_r[i]    = pos[2 * b];
            s_c[i]    = pos[2 * b + 1];
        } else {
            s_base[i] = 0;
            s_r[i]    = 1 << 20;
            s_c[i]    = 1 << 20;
        }
    }
    __syncthreads();

    const int x     = threadIdx.x & 63;
    const int phase = threadIdx.x >> 6;
    const int X     = X0 + x;
    const int Ya    = Y0 + phase;
    const int Yb    = Ya + 4;

    const int MS = NB * PH * PW;

    float acc_a = 0.0f;
    float acc_b = 0.0f;

    #pragma unroll 4
    for (int i = 0; i < cpad; ++i) {
        const int dra = Ya - s_r[i];
        const int drb = Yb - s_r[i];
        const int dc  = X  - s_c[i];

        const bool va = ((unsigned)dc < (unsigned)PW) &
                        ((unsigned)dra < (unsigned)PH);
        const bool vb = ((unsigned)dc < (unsigned)PW) &
                        ((unsigned)drb < (unsigned)PH);

        const int dcc  = min(max(dc, 0),  PW - 1);
        const int drac = min(max(dra, 0), PH - 1);
        const int drbc = min(max(drb, 0), PH - 1);

        const float* wa = waves + s_base[i] + drac * PW + dcc;
        const float* wb = waves + s_base[i] + drbc * PW + dcc;

        const float a0 = wa[0];
        const float a1 = wa[MS];
        const float a2 = wa[2 * MS];
        const float a3 = wa[3 * MS];
        const float b0 = wb[0];
        const float b1 = wb[MS];
        const float b2 = wb[2 * MS];
        const float b3 = wb[3 * MS];

        const float sa = a0 * a0 + a1 * a1 + a2 * a2 + a3 * a3;
        const float sb = b0 * b0 + b1 * b1 + b2 * b2 + b3 * b3;
        acc_a += va ? sa : 0.0f;
        acc_b += vb ? sb : 0.0f;
    }

    norm[Ya * OW + X] = acc_a;
    norm[Yb * OW + X] = acc_b;
}

extern "C" void kernel_launch(void* const* d_in, const int* in_sizes, int n_in,
                              void* d_out, int out_size, void* d_ws, size_t ws_size,
                              hipStream_t stream) {
    const float* obj   = (const float*)d_in[0];
    const float* waves = (const float*)d_in[1];
    const int*   pos   = (const int*)d_in[2];

    float* patches = (float*)d_out;                        // 16,777,216 elems
    float* norm    = (float*)d_out + (size_t)NB * PH * PW; // 4,194,304 elems

    // Workspace layout:
    //   [tile_cnt: NT ints][tile_list: NT*CAP ints][patch_norm: NB*PH*PW f32]
    //   = 4 KB + 512 KB + 64 MiB (observed ws poison fill = 1 GiB -> fits)
    int*   tile_cnt  = (int*)d_ws;
    int*   tile_list = tile_cnt + NT;
    float* pnorm     = (float*)(tile_list + (size_t)NT * CAP);

    const size_t ws_need = (size_t)(NT + (size_t)NT * CAP) * sizeof(int)
                         + (size_t)NB * PH * PW * sizeof(float);

    // ws is poisoned 0xAA each call -> zero the counters (4 KB, async).
    hipMemsetAsync(tile_cnt, 0, NT * sizeof(int), stream);

    const int quads = NB * PH * PW / 4;  // 4,194,304

    if (ws_size >= ws_need) {
        crop_reduce_bin<<<quads / 256, 256, 0, stream>>>(
            obj, waves, pos, patches, pnorm, tile_cnt, tile_list);
        // Stream order guarantees pnorm + tile lists are complete & visible.
        norm_gather_pn<<<NT * SLICES, 256, 0, stream>>>(
            pnorm, pos, tile_cnt, tile_list, norm);
    } else {
        crop_and_bin<<<quads / 256, 256, 0, stream>>>(
            obj, pos, patches, tile_cnt, tile_list);
        norm_gather_waves<<<NT * SLICES, 256, 0, stream>>>(
            waves, pos, tile_cnt, tile_list, norm);
    }
}

// Round 2
// 430.120 us; speedup vs baseline: 1.0021x; 1.0021x over previous
//
#include <hip/hip_runtime.h>

// Problem constants (from reference):
//   obj   : [1, 2048, 2048] fp32      (in_sizes[0] = 4,194,304)
//   waves : [4, 1024, 128, 128] fp32  (in_sizes[1] = 67,108,864)
//   pos   : [1024, 2] int32           (in_sizes[2] = 2,048), values in [0,1920)
// Outputs (concatenated in d_out, fp32):
//   patches     : [1024, 1, 128, 128] = 16,777,216 elems
//   object_norm : [2048, 2048]        =  4,194,304 elems
//
// R2: revert the pnorm round-trip (R1 post-mortem: +19us, exactly the extra
// 128 MB HBM; the gathered waves re-reads were L2/L3-served so the saving
// never materialized). Attack the remaining slack instead: gather request
// amplification. TS 64->32 cuts per-entry wasted pixels (per-dim overlap
// 42.7/64 -> 25.8/32), request volume ~603 MB -> ~415 MB. One block per
// 32x32 tile, 256 threads, 4 pixels/thread (rows phase+{0,8,16,24}).

#define NMODES 4
#define NB     1024
#define PH     128
#define PW     128
#define OH     2048
#define OW     2048

#define TS       32              // object tile size (32x32)
#define NT_X     (OW / TS)       // 64
#define NT_Y     (OH / TS)       // 64
#define NT       (NT_X * NT_Y)   // 4096 tiles
#define CAP      64              // max batches per tile (avg ~6, Poisson tail << 64)
#define UNROLL   4               // list padding granularity

// ---------------------------------------------------------------------------
// Kernel A: patch crop (gather from obj, L3-resident) + batch->tile binning.
// One thread per aligned quad of 4 consecutive w elements.
// ---------------------------------------------------------------------------
__global__ __launch_bounds__(256) void crop_and_bin(
    const float* __restrict__ obj,
    const int*   __restrict__ pos,
    float* __restrict__ patches,
    int*   __restrict__ tile_cnt,
    int*   __restrict__ tile_list)
{
    const int q = blockIdx.x * blockDim.x + threadIdx.x;

    // --- binning (first NB threads only; ~25 tiny int atomics each) ---
    if (q < NB) {
        const int r0 = pos[2 * q];
        const int c0 = pos[2 * q + 1];
        const int ty0 = r0 >> 5, ty1 = (r0 + PH - 1) >> 5;
        const int tx0 = c0 >> 5, tx1 = (c0 + PW - 1) >> 5;
        for (int ty = ty0; ty <= ty1; ++ty)
            for (int tx = tx0; tx <= tx1; ++tx) {
                const int t = ty * NT_X + tx;
                const int idx = atomicAdd(&tile_cnt[t], 1);
                if (idx < CAP) tile_list[t * CAP + idx] = q;
            }
    }

    // --- crop: patches[b,h,w..w+3] = obj[r0+h, c0+w..w+3] ---
    const int b     = q >> 12;          // quads per batch = PH*PW/4 = 4096
    const int local = q & 4095;
    const int h     = local >> 5;       // 32 quads per row
    const int w     = (local & 31) << 2;

    const int r0 = pos[b * 2 + 0];
    const int c0 = pos[b * 2 + 1];

    const int oidx = (r0 + h) * OW + (c0 + w);
    float4 p;
    p.x = obj[oidx + 0];
    p.y = obj[oidx + 1];
    p.z = obj[oidx + 2];
    p.w = obj[oidx + 3];
    *reinterpret_cast<float4*>(patches + b * (PH * PW) + h * PW + w) = p;
}

// ---------------------------------------------------------------------------
// Kernel B: object_norm via gather from waves. 4096 blocks = one per 32x32
// tile. 256 threads/block; each thread owns 4 pixels (same x, rows
// phase+{0,8,16,24}). Branchless: loads clamped into the patch so every
// load is legal and issued unconditionally; accumulate is masked. Tile
// lists padded to a multiple of UNROLL with far-away dummy positions.
// ---------------------------------------------------------------------------
__global__ __launch_bounds__(256) void norm_gather(
    const float* __restrict__ waves,
    const int*   __restrict__ pos,
    const int*   __restrict__ tile_cnt,
    const int*   __restrict__ tile_list,
    float* __restrict__ norm)
{
    const int t  = blockIdx.x;          // tile id
    const int Y0 = (t >> 6) * TS;       // NT_X = 64
    const int X0 = (t & 63) * TS;

    __shared__ int s_base[CAP + UNROLL];   // b * PH*PW
    __shared__ int s_r[CAP + UNROLL];
    __shared__ int s_c[CAP + UNROLL];

    const int count = min(tile_cnt[t], CAP);
    const int cpad  = (count + UNROLL - 1) & ~(UNROLL - 1);
    for (int i = threadIdx.x; i < cpad; i += 256) {
        if (i < count) {
            const int b = tile_list[t * CAP + i];
            s_base[i] = b * (PH * PW);
            s_r[i]    = pos[2 * b];
            s_c[i]    = pos[2 * b + 1];
        } else {
            s_base[i] = 0;              // dummy: mask always 0; clamped
            s_r[i]    = 1 << 20;        // loads hit waves[0..] (safe)
            s_c[i]    = 1 << 20;
        }
    }
    __syncthreads();

    const int x     = threadIdx.x & 31; // 32 lanes span one tile row
    const int phase = threadIdx.x >> 5; // 0..7
    const int X     = X0 + x;
    const int Y     = Y0 + phase;       // rows Y, Y+8, Y+16, Y+24

    const int MS = NB * PH * PW;        // mode stride in elements

    float acc0 = 0.0f, acc1 = 0.0f, acc2 = 0.0f, acc3 = 0.0f;

    #pragma unroll 2
    for (int i = 0; i < cpad; ++i) {
        const int r0 = s_r[i];          // broadcast LDS reads (conflict-free)
        const int c0 = s_c[i];
        const int bb = s_base[i];

        const int dc  = X - c0;
        const bool vc = (unsigned)dc < (unsigned)PW;
        const int dcc = min(max(dc, 0), PW - 1);

        const int dr0 = Y      - r0;
        const int dr1 = Y + 8  - r0;
        const int dr2 = Y + 16 - r0;
        const int dr3 = Y + 24 - r0;

        const bool v0 = vc & ((unsigned)dr0 < (unsigned)PH);
        const bool v1 = vc & ((unsigned)dr1 < (unsigned)PH);
        const bool v2 = vc & ((unsigned)dr2 < (unsigned)PH);
        const bool v3 = vc & ((unsigned)dr3 < (unsigned)PH);

        const int drc0 = min(max(dr0, 0), PH - 1);
        const int drc1 = min(max(dr1, 0), PH - 1);
        const int drc2 = min(max(dr2, 0), PH - 1);
        const int drc3 = min(max(dr3, 0), PH - 1);

        const float* w0p = waves + bb + drc0 * PW + dcc;
        const float* w1p = waves + bb + drc1 * PW + dcc;
        const float* w2p = waves + bb + drc2 * PW + dcc;
        const float* w3p = waves + bb + drc3 * PW + dcc;

        // 16 independent loads -> deep MLP; mostly L2/L3 hits
        const float a0 = w0p[0], a1 = w0p[MS], a2 = w0p[2 * MS], a3 = w0p[3 * MS];
        const float b0 = w1p[0], b1 = w1p[MS], b2 = w1p[2 * MS], b3 = w1p[3 * MS];
        const float c0f = w2p[0], c1 = w2p[MS], c2 = w2p[2 * MS], c3 = w2p[3 * MS];
        const float d0 = w3p[0], d1 = w3p[MS], d2 = w3p[2 * MS], d3 = w3p[3 * MS];

        const float s0 = a0 * a0 + a1 * a1 + a2 * a2 + a3 * a3;
        const float s1 = b0 * b0 + b1 * b1 + b2 * b2 + b3 * b3;
        const float s2 = c0f * c0f + c1 * c1 + c2 * c2 + c3 * c3;
        const float s3 = d0 * d0 + d1 * d1 + d2 * d2 + d3 * d3;

        acc0 += v0 ? s0 : 0.0f;         // v_cndmask + v_add (no branch)
        acc1 += v1 ? s1 : 0.0f;
        acc2 += v2 ? s2 : 0.0f;
        acc3 += v3 ? s3 : 0.0f;
    }

    norm[(Y     ) * OW + X] = acc0;     // every pixel written exactly once
    norm[(Y +  8) * OW + X] = acc1;
    norm[(Y + 16) * OW + X] = acc2;
    norm[(Y + 24) * OW + X] = acc3;
}

extern "C" void kernel_launch(void* const* d_in, const int* in_sizes, int n_in,
                              void* d_out, int out_size, void* d_ws, size_t ws_size,
                              hipStream_t stream) {
    const float* obj   = (const float*)d_in[0];
    const float* waves = (const float*)d_in[1];
    const int*   pos   = (const int*)d_in[2];

    float* patches = (float*)d_out;                        // 16,777,216 elems
    float* norm    = (float*)d_out + (size_t)NB * PH * PW; // 4,194,304 elems

    // Workspace layout: [tile_cnt: NT ints][tile_list: NT*CAP ints] ~ 1 MB
    int* tile_cnt  = (int*)d_ws;
    int* tile_list = tile_cnt + NT;

    // ws is poisoned each call -> zero the counters (16 KB, async).
    hipMemsetAsync(tile_cnt, 0, NT * sizeof(int), stream);

    const int quads = NB * PH * PW / 4;  // 4,194,304
    crop_and_bin<<<quads / 256, 256, 0, stream>>>(obj, pos, patches,
                                                  tile_cnt, tile_list);
    // Stream order guarantees tile lists are complete & visible device-wide.
    norm_gather<<<NT, 256, 0, stream>>>(waves, pos, tile_cnt,
                                        tile_list, norm);
}